// Round 2
// baseline (576.510 us; speedup 1.0000x reference)
//
#include <hip/hip_runtime.h>
#include <math.h>

#define D_MODEL 256
#define NQ 2048
#define M_KEYS 65536
#define CAP 512
#define RESCORE 64
#define TOPK 32
#define ZTHRESH 2.8f    // per-query z-score threshold (sigma units of that query's score dist)
#define QT 128
#define KT 128
#define NCHUNK 16
#define CHUNK_SZ 4096
#define LSTRIDE 264     // 256 + 8 f16 pad: row stride 528B -> 2-way LDS bank alias (free)

typedef _Float16 half8v __attribute__((ext_vector_type(8)));
typedef _Float16 half4v __attribute__((ext_vector_type(4)));
typedef float floatx4 __attribute__((ext_vector_type(4)));

// ---------------- fp32 -> fp16 conversion (elementwise) ----------------
__global__ __launch_bounds__(256) void cvt_f32_f16(const float* __restrict__ src,
                                                   _Float16* __restrict__ dst, int n4) {
  int i = blockIdx.x * 256 + threadIdx.x;
  if (i < n4) {
    const float4 v = ((const float4*)src)[i];
    half4v h = {(_Float16)v.x, (_Float16)v.y, (_Float16)v.z, (_Float16)v.w};
    ((half4v*)dst)[i] = h;
  }
}

// ---------------- per-query threshold: tau_dot[q] = Z * ||q_row|| ----------------
// grid NQ/4 blocks x 256 threads; wave w handles query blockIdx.x*4 + w
__global__ __launch_bounds__(256) void qtau_kernel(const float* __restrict__ qf,
                                                   float* __restrict__ qtau) {
  const int lane = threadIdx.x & 63;
  const int q = blockIdx.x * 4 + (threadIdx.x >> 6);
  const float4 v = ((const float4*)(qf + (size_t)q * D_MODEL))[lane];
  float ss = v.x * v.x + v.y * v.y + v.z * v.z + v.w * v.w;
#pragma unroll
  for (int off = 32; off > 0; off >>= 1) ss += __shfl_down(ss, off);
  if (lane == 0) qtau[q] = ZTHRESH * sqrtf(ss);
}

// ---------------- phase 1: f16 MFMA scores + per-query threshold filter ----------------
// grid: (NQ/QT query tiles) x (NCHUNK key chunks); block 256 = 4 waves (2x2 of 64q x 64k)
__global__ __launch_bounds__(256) void phase1_kernel(
    const _Float16* __restrict__ qh, const _Float16* __restrict__ kh,
    const float* __restrict__ qtau,
    float* __restrict__ cand_s, int* __restrict__ cand_i, int* __restrict__ cnt) {
  __shared__ _Float16 qs[QT][LSTRIDE];  // 67.5 KB
  __shared__ _Float16 ks[KT][LSTRIDE];  // 67.5 KB  (total 135 KB <= 160 KB)

  const int tid = threadIdx.x;
  const int qbase = blockIdx.x * QT;
  const int kchunk = blockIdx.y * CHUNK_SZ;

  // stage whole Q tile (128 x 256 f16) once
  for (int i = tid; i < QT * (D_MODEL / 8); i += 256) {
    int r = i >> 5, c = (i & 31) << 3;
    *(uint4*)(&qs[r][c]) = *(const uint4*)(&qh[(size_t)(qbase + r) * D_MODEL + c]);
  }

  const int lane = tid & 63;
  const int wave = tid >> 6;
  const int wr = (wave >> 1) << 6;   // wave's query offset (0/64)
  const int wc = (wave & 1) << 6;    // wave's key offset   (0/64)
  const int lrow = lane & 15;        // A/B fragment row (m / n)
  const int lk8 = (lane >> 4) << 3;  // k-offset within 32-wide K step

  // per-lane thresholds for the 16 query rows this lane's accumulators cover
  const int qrow0 = qbase + wr + ((lane >> 4) << 2);
  float taur[4][4];
#pragma unroll
  for (int mi = 0; mi < 4; ++mi)
#pragma unroll
    for (int r = 0; r < 4; ++r) taur[mi][r] = qtau[qrow0 + mi * 16 + r];

  for (int st = 0; st < CHUNK_SZ / KT; ++st) {
    const int kbase = kchunk + st * KT;
    __syncthreads();  // protect ks from previous iteration's readers (also covers qs 1st iter)
    for (int i = tid; i < KT * (D_MODEL / 8); i += 256) {
      int r = i >> 5, c = (i & 31) << 3;
      *(uint4*)(&ks[r][c]) = *(const uint4*)(&kh[(size_t)(kbase + r) * D_MODEL + c]);
    }
    __syncthreads();

    floatx4 acc[4][4] = {};
#pragma unroll
    for (int kk = 0; kk < D_MODEL; kk += 32) {
      half8v a[4], b[4];
#pragma unroll
      for (int mi = 0; mi < 4; ++mi)
        a[mi] = *(const half8v*)(&qs[wr + mi * 16 + lrow][kk + lk8]);
#pragma unroll
      for (int ni = 0; ni < 4; ++ni)
        b[ni] = *(const half8v*)(&ks[wc + ni * 16 + lrow][kk + lk8]);
#pragma unroll
      for (int mi = 0; mi < 4; ++mi)
#pragma unroll
        for (int ni = 0; ni < 4; ++ni)
          acc[mi][ni] = __builtin_amdgcn_mfma_f32_16x16x32_f16(a[mi], b[ni], acc[mi][ni], 0, 0, 0);
    }

    // C/D layout (verified m89/m91): col = lane&15, row = (lane>>4)*4 + reg
#pragma unroll
    for (int mi = 0; mi < 4; ++mi) {
#pragma unroll
      for (int ni = 0; ni < 4; ++ni) {
        const int kidx = kbase + wc + ni * 16 + lrow;
#pragma unroll
        for (int r = 0; r < 4; ++r) {
          float dot = acc[mi][ni][r];
          if (dot > taur[mi][r]) {
            int q = qrow0 + mi * 16 + r;
            int pos = atomicAdd(&cnt[q], 1);
            if (pos < CAP) {
              cand_s[(size_t)q * CAP + pos] = dot * 0.0625f;
              cand_i[(size_t)q * CAP + pos] = kidx;
            }
          }
        }
      }
    }
  }
}

// ---------------- phase 2: per-query select/rescore/softmax/aggregate ----------------
__global__ __launch_bounds__(256) void phase2_kernel(
    const float* __restrict__ qf, const float* __restrict__ keys,
    const float* __restrict__ vals, const float* __restrict__ cand_s,
    const int* __restrict__ cand_i, const int* __restrict__ cnt,
    float* __restrict__ out) {
  __shared__ float sc[CAP];
  __shared__ int si[CAP];
  __shared__ float xs[RESCORE];
  __shared__ int xi[RESCORE];
  __shared__ float ew[TOPK];
  __shared__ float invsum;

  const int qid = blockIdx.x;
  const int tid = threadIdx.x;
  int c = cnt[qid];
  if (c > CAP) c = CAP;

  for (int i = tid; i < CAP; i += 256) {
    bool valid = (i < c);
    sc[i] = valid ? cand_s[(size_t)qid * CAP + i] : -1e30f;
    si[i] = valid ? cand_i[(size_t)qid * CAP + i] : -1;
  }

  // bitonic sort descending by approx (f16-derived) score, N = 512
  for (int k = 2; k <= CAP; k <<= 1) {
    for (int j = k >> 1; j > 0; j >>= 1) {
      __syncthreads();
      for (int t = tid; t < CAP; t += 256) {
        int p = t ^ j;
        if (p > t) {
          float a = sc[t], b = sc[p];
          bool desc = ((t & k) == 0);
          if (desc ? (a < b) : (a > b)) {
            sc[t] = b; sc[p] = a;
            int tmp = si[t]; si[t] = si[p]; si[p] = tmp;
          }
        }
      }
    }
  }
  __syncthreads();

  // exact rescore (fp64 accumulate) of the top-64 candidates; one wave per candidate group
  const int lane = tid & 63, wv = tid >> 6;
  const float4 qv = ((const float4*)(qf + (size_t)qid * D_MODEL))[lane];
  for (int cand = wv; cand < RESCORE; cand += 4) {
    int kidx = si[cand];  // wave-uniform
    float sres = -1e30f;
    if (kidx >= 0) {
      const float4 kv = ((const float4*)(keys + (size_t)kidx * D_MODEL))[lane];
      double p = (double)qv.x * kv.x + (double)qv.y * kv.y +
                 (double)qv.z * kv.z + (double)qv.w * kv.w;
#pragma unroll
      for (int off = 32; off > 0; off >>= 1) p += __shfl_down(p, off);
      sres = (float)(p * 0.0625);
    }
    if (lane == 0) { xs[cand] = sres; xi[cand] = kidx; }
  }
  __syncthreads();

  // bitonic sort descending by exact score, N = 64
  for (int k = 2; k <= RESCORE; k <<= 1) {
    for (int j = k >> 1; j > 0; j >>= 1) {
      __syncthreads();
      if (tid < RESCORE) {
        int t = tid, p = t ^ j;
        if (p > t) {
          float a = xs[t], b = xs[p];
          bool desc = ((t & k) == 0);
          if (desc ? (a < b) : (a > b)) {
            xs[t] = b; xs[p] = a;
            int tmp = xi[t]; xi[t] = xi[p]; xi[p] = tmp;
          }
        }
      }
    }
  }
  __syncthreads();

  // softmax over exact top-32 (xs[0] is the max — sorted)
  if (tid < TOPK) ew[tid] = expf(xs[tid] - xs[0]);
  __syncthreads();
  if (tid == 0) {
    float s = 0.f;
    for (int i = 0; i < TOPK; ++i) s += ew[i];
    invsum = 1.0f / s;
  }
  __syncthreads();

  // aggregate: thread d owns output dim d; coalesced value rows
  float acc = 0.f;
#pragma unroll 4
  for (int i = 0; i < TOPK; ++i)
    acc += (ew[i] * invsum) * vals[(size_t)xi[i] * D_MODEL + tid];
  out[(size_t)qid * D_MODEL + tid] = acc;
}

// ---------------- launcher ----------------
extern "C" void kernel_launch(void* const* d_in, const int* in_sizes, int n_in,
                              void* d_out, int out_size, void* d_ws, size_t ws_size,
                              hipStream_t stream) {
  const float* q = (const float*)d_in[0];   // [2048, 256]
  const float* k = (const float*)d_in[1];   // [65536, 256]
  const float* v = (const float*)d_in[2];   // [65536, 256]
  float* out = (float*)d_out;               // [2048, 256]

  char* ws = (char*)d_ws;
  _Float16* kh = (_Float16*)ws;                      // 33,554,432 B
  _Float16* qh = (_Float16*)(ws + 33554432);         //  1,048,576 B
  float* cand_s = (float*)(ws + 34603008);           //  4,194,304 B
  int* cand_i = (int*)(ws + 38797312);               //  4,194,304 B
  int* cnt = (int*)(ws + 42991616);                  //      8,192 B
  float* qtau = (float*)(ws + 42999808);             //      8,192 B  (total ~43 MB)

  hipMemsetAsync(cnt, 0, NQ * sizeof(int), stream);
  cvt_f32_f16<<<(M_KEYS * D_MODEL / 4 + 255) / 256, 256, 0, stream>>>(k, kh, M_KEYS * D_MODEL / 4);
  cvt_f32_f16<<<(NQ * D_MODEL / 4 + 255) / 256, 256, 0, stream>>>(q, qh, NQ * D_MODEL / 4);
  qtau_kernel<<<NQ / 4, 256, 0, stream>>>(q, qtau);

  dim3 g1(NQ / QT, NCHUNK);
  phase1_kernel<<<g1, 256, 0, stream>>>(qh, kh, qtau, cand_s, cand_i, cnt);
  phase2_kernel<<<NQ, 256, 0, stream>>>(q, k, v, cand_s, cand_i, cnt, out);
}

// Round 3
// 378.408 us; speedup vs baseline: 1.5235x; 1.5235x over previous
//
#include <hip/hip_runtime.h>
#include <math.h>

#define D_MODEL 256
#define NQ 2048
#define M_KEYS 65536
#define CAP 512
#define RESCORE 64
#define TOPK 32
#define ZTHRESH 2.8f    // per-query z-score threshold (sigma units of that query's score dist)
#define QT 128
#define KTILE 128
#define BK 64

typedef _Float16 half8v __attribute__((ext_vector_type(8)));
typedef _Float16 half4v __attribute__((ext_vector_type(4)));
typedef float floatx4 __attribute__((ext_vector_type(4)));

__device__ __forceinline__ void async_load16(const _Float16* g, _Float16* l) {
  __builtin_amdgcn_global_load_lds(
      (const __attribute__((address_space(1))) void*)g,
      (__attribute__((address_space(3))) void*)l, 16, 0, 0);
}

// ---------------- fp32 -> fp16 conversion (elementwise) ----------------
__global__ __launch_bounds__(256) void cvt_f32_f16(const float* __restrict__ src,
                                                   _Float16* __restrict__ dst, int n4) {
  int i = blockIdx.x * 256 + threadIdx.x;
  if (i < n4) {
    const float4 v = ((const float4*)src)[i];
    half4v h = {(_Float16)v.x, (_Float16)v.y, (_Float16)v.z, (_Float16)v.w};
    ((half4v*)dst)[i] = h;
  }
}

// ---------------- per-query threshold: tau_dot[q] = Z * ||q_row|| ----------------
__global__ __launch_bounds__(256) void qtau_kernel(const float* __restrict__ qf,
                                                   float* __restrict__ qtau) {
  const int lane = threadIdx.x & 63;
  const int q = blockIdx.x * 4 + (threadIdx.x >> 6);
  const float4 v = ((const float4*)(qf + (size_t)q * D_MODEL))[lane];
  float ss = v.x * v.x + v.y * v.y + v.z * v.z + v.w * v.w;
#pragma unroll
  for (int off = 32; off > 0; off >>= 1) ss += __shfl_down(ss, off);
  if (lane == 0) qtau[q] = ZTHRESH * sqrtf(ss);
}

// ---------------- phase 1: m97-style 128x128 tile, BK=64, global_load_lds ----------------
// grid: (NQ/128) x (M_KEYS/128) = 16 x 512 = 8192 blocks; 256 thr = 4 waves (2x2 of 64q x 64k)
__global__ __launch_bounds__(256) void phase1_kernel(
    const _Float16* __restrict__ qh, const _Float16* __restrict__ kh,
    const float* __restrict__ qtau,
    float* __restrict__ cand_s, int* __restrict__ cand_i, int* __restrict__ cnt) {
  __shared__ __align__(16) _Float16 As[QT * BK];     // 16 KB
  __shared__ __align__(16) _Float16 Bs[KTILE * BK];  // 16 KB (total 32 KB)

  const int tid = threadIdx.x;
  const int lane = tid & 63;
  const int wave = tid >> 6;
  const int qbase = blockIdx.x * QT;
  const int kbase = blockIdx.y * KTILE;

  // staging map: wave w covers rows [32w,32w+32); instr j covers 8 rows (1 KB).
  // lane i -> row +i/8, col f16 (i%8)*8  (HW writes LDS at wavebase + lane*16)
  const int srow = wave * 32 + (lane >> 3);
  const int scol = (lane & 7) * 8;
  const _Float16* gA = qh + (size_t)(qbase + srow) * D_MODEL + scol;
  const _Float16* gB = kh + (size_t)(kbase + srow) * D_MODEL + scol;
  _Float16* lA = As + (wave * 32) * BK;
  _Float16* lB = Bs + (wave * 32) * BK;

  const int wr = (wave >> 1) << 6;   // wave's query offset (0/64)
  const int wc = (wave & 1) << 6;    // wave's key offset   (0/64)
  const int lrow = lane & 15;
  const int lk8 = (lane >> 4) << 3;

  floatx4 acc[4][4] = {};

#pragma unroll
  for (int kt = 0; kt < D_MODEL / BK; ++kt) {
    const int k0 = kt * BK;
    __syncthreads();  // previous iteration's LDS readers done
#pragma unroll
    for (int j = 0; j < 4; ++j) {
      async_load16(gA + (size_t)(j * 8) * D_MODEL + k0, lA + (j * 8) * BK);
      async_load16(gB + (size_t)(j * 8) * D_MODEL + k0, lB + (j * 8) * BK);
    }
    __syncthreads();  // vmcnt(0) drain + barrier

#pragma unroll
    for (int kk = 0; kk < BK; kk += 32) {
      half8v a[4], b[4];
#pragma unroll
      for (int mi = 0; mi < 4; ++mi)
        a[mi] = *(const half8v*)(&As[(wr + mi * 16 + lrow) * BK + kk + lk8]);
#pragma unroll
      for (int ni = 0; ni < 4; ++ni)
        b[ni] = *(const half8v*)(&Bs[(wc + ni * 16 + lrow) * BK + kk + lk8]);
#pragma unroll
      for (int mi = 0; mi < 4; ++mi)
#pragma unroll
        for (int ni = 0; ni < 4; ++ni)
          acc[mi][ni] = __builtin_amdgcn_mfma_f32_16x16x32_f16(a[mi], b[ni], acc[mi][ni], 0, 0, 0);
    }
  }

  // epilogue: per-query threshold filter. C/D layout: col=lane&15, row=(lane>>4)*4+reg
  const int qrow0 = qbase + wr + ((lane >> 4) << 2);
#pragma unroll
  for (int mi = 0; mi < 4; ++mi) {
#pragma unroll
    for (int r = 0; r < 4; ++r) {
      const int q = qrow0 + mi * 16 + r;
      const float tau = qtau[q];
#pragma unroll
      for (int ni = 0; ni < 4; ++ni) {
        float dot = acc[mi][ni][r];
        if (dot > tau) {
          int kidx = kbase + wc + ni * 16 + lrow;
          int pos = atomicAdd(&cnt[q], 1);
          if (pos < CAP) {
            cand_s[(size_t)q * CAP + pos] = dot * 0.0625f;
            cand_i[(size_t)q * CAP + pos] = kidx;
          }
        }
      }
    }
  }
}

// ---------------- phase 2: per-query select/rescore/softmax/aggregate ----------------
__global__ __launch_bounds__(256) void phase2_kernel(
    const float* __restrict__ qf, const float* __restrict__ keys,
    const float* __restrict__ vals, const float* __restrict__ cand_s,
    const int* __restrict__ cand_i, const int* __restrict__ cnt,
    float* __restrict__ out) {
  __shared__ float sc[CAP];
  __shared__ int si[CAP];
  __shared__ float xs[RESCORE];
  __shared__ int xi[RESCORE];
  __shared__ float ew[TOPK];
  __shared__ float invsum;

  const int qid = blockIdx.x;
  const int tid = threadIdx.x;
  int c = cnt[qid];
  if (c > CAP) c = CAP;
  const int n = (c <= 256) ? 256 : CAP;  // block-uniform sort width

  for (int i = tid; i < n; i += 256) {
    bool valid = (i < c);
    sc[i] = valid ? cand_s[(size_t)qid * CAP + i] : -1e30f;
    si[i] = valid ? cand_i[(size_t)qid * CAP + i] : -1;
  }

  // bitonic sort descending by approx (f16-derived) score, width n
  for (int k = 2; k <= n; k <<= 1) {
    for (int j = k >> 1; j > 0; j >>= 1) {
      __syncthreads();
      for (int t = tid; t < n; t += 256) {
        int p = t ^ j;
        if (p > t) {
          float a = sc[t], b = sc[p];
          bool desc = ((t & k) == 0);
          if (desc ? (a < b) : (a > b)) {
            sc[t] = b; sc[p] = a;
            int tmp = si[t]; si[t] = si[p]; si[p] = tmp;
          }
        }
      }
    }
  }
  __syncthreads();

  // exact rescore (fp64 accumulate) of the top-64 candidates
  const int lane = tid & 63, wv = tid >> 6;
  const float4 qv = ((const float4*)(qf + (size_t)qid * D_MODEL))[lane];
  for (int cand = wv; cand < RESCORE; cand += 4) {
    int kidx = si[cand];  // wave-uniform
    float sres = -1e30f;
    if (kidx >= 0) {
      const float4 kv = ((const float4*)(keys + (size_t)kidx * D_MODEL))[lane];
      double p = (double)qv.x * kv.x + (double)qv.y * kv.y +
                 (double)qv.z * kv.z + (double)qv.w * kv.w;
#pragma unroll
      for (int off = 32; off > 0; off >>= 1) p += __shfl_down(p, off);
      sres = (float)(p * 0.0625);
    }
    if (lane == 0) { xs[cand] = sres; xi[cand] = kidx; }
  }
  __syncthreads();

  // bitonic sort descending by exact score, N = 64
  for (int k = 2; k <= RESCORE; k <<= 1) {
    for (int j = k >> 1; j > 0; j >>= 1) {
      __syncthreads();
      if (tid < RESCORE) {
        int t = tid, p = t ^ j;
        if (p > t) {
          float a = xs[t], b = xs[p];
          bool desc = ((t & k) == 0);
          if (desc ? (a < b) : (a > b)) {
            xs[t] = b; xs[p] = a;
            int tmp = xi[t]; xi[t] = xi[p]; xi[p] = tmp;
          }
        }
      }
    }
  }
  __syncthreads();

  // softmax over exact top-32 (xs[0] is the max — sorted)
  if (tid < TOPK) ew[tid] = expf(xs[tid] - xs[0]);
  __syncthreads();
  if (tid == 0) {
    float s = 0.f;
    for (int i = 0; i < TOPK; ++i) s += ew[i];
    invsum = 1.0f / s;
  }
  __syncthreads();

  // aggregate: thread d owns output dim d; coalesced value rows
  float acc = 0.f;
#pragma unroll 4
  for (int i = 0; i < TOPK; ++i)
    acc += (ew[i] * invsum) * vals[(size_t)xi[i] * D_MODEL + tid];
  out[(size_t)qid * D_MODEL + tid] = acc;
}

// ---------------- launcher ----------------
extern "C" void kernel_launch(void* const* d_in, const int* in_sizes, int n_in,
                              void* d_out, int out_size, void* d_ws, size_t ws_size,
                              hipStream_t stream) {
  const float* q = (const float*)d_in[0];   // [2048, 256]
  const float* k = (const float*)d_in[1];   // [65536, 256]
  const float* v = (const float*)d_in[2];   // [65536, 256]
  float* out = (float*)d_out;               // [2048, 256]

  char* ws = (char*)d_ws;
  _Float16* kh = (_Float16*)ws;                      // 33,554,432 B
  _Float16* qh = (_Float16*)(ws + 33554432);         //  1,048,576 B
  float* cand_s = (float*)(ws + 34603008);           //  4,194,304 B
  int* cand_i = (int*)(ws + 38797312);               //  4,194,304 B
  int* cnt = (int*)(ws + 42991616);                  //      8,192 B
  float* qtau = (float*)(ws + 42999808);             //      8,192 B

  hipMemsetAsync(cnt, 0, NQ * sizeof(int), stream);
  cvt_f32_f16<<<(M_KEYS * D_MODEL / 4 + 255) / 256, 256, 0, stream>>>(k, kh, M_KEYS * D_MODEL / 4);
  cvt_f32_f16<<<(NQ * D_MODEL / 4 + 255) / 256, 256, 0, stream>>>(q, qh, NQ * D_MODEL / 4);
  qtau_kernel<<<NQ / 4, 256, 0, stream>>>(q, qtau);

  dim3 g1(NQ / QT, M_KEYS / KTILE);
  phase1_kernel<<<g1, 256, 0, stream>>>(qh, kh, qtau, cand_s, cand_i, cnt);
  phase2_kernel<<<NQ, 256, 0, stream>>>(q, k, v, cand_s, cand_i, cnt, out);
}

// Round 4
// 374.149 us; speedup vs baseline: 1.5409x; 1.0114x over previous
//
#include <hip/hip_runtime.h>
#include <math.h>

#define D_MODEL 256
#define NQ 2048
#define M_KEYS 65536
#define CAP 512
#define RESCORE 64
#define TOPK 32
#define ZTHRESH 2.8f    // per-query z-score threshold (sigma units of that query's score dist)
#define QT 128
#define KTILE 128
#define BK 64

typedef _Float16 half8v __attribute__((ext_vector_type(8)));
typedef _Float16 half4v __attribute__((ext_vector_type(4)));
typedef float floatx4 __attribute__((ext_vector_type(4)));

__device__ __forceinline__ void async_load16(const _Float16* g, _Float16* l) {
  __builtin_amdgcn_global_load_lds(
      (const __attribute__((address_space(1))) void*)g,
      (__attribute__((address_space(3))) void*)l, 16, 0, 0);
}

// ---------------- fp32 -> fp16 conversion (elementwise) ----------------
__global__ __launch_bounds__(256) void cvt_f32_f16(const float* __restrict__ src,
                                                   _Float16* __restrict__ dst, int n4) {
  int i = blockIdx.x * 256 + threadIdx.x;
  if (i < n4) {
    const float4 v = ((const float4*)src)[i];
    half4v h = {(_Float16)v.x, (_Float16)v.y, (_Float16)v.z, (_Float16)v.w};
    ((half4v*)dst)[i] = h;
  }
}

// ---------------- per-query threshold: tau_dot[q] = Z * ||q_row|| ----------------
__global__ __launch_bounds__(256) void qtau_kernel(const float* __restrict__ qf,
                                                   float* __restrict__ qtau) {
  const int lane = threadIdx.x & 63;
  const int q = blockIdx.x * 4 + (threadIdx.x >> 6);
  const float4 v = ((const float4*)(qf + (size_t)q * D_MODEL))[lane];
  float ss = v.x * v.x + v.y * v.y + v.z * v.z + v.w * v.w;
#pragma unroll
  for (int off = 32; off > 0; off >>= 1) ss += __shfl_down(ss, off);
  if (lane == 0) qtau[q] = ZTHRESH * sqrtf(ss);
}

// ---------------- phase 1: 128x128 tile, BK=64, global_load_lds, XOR-swizzled LDS ----
// LDS(row, c8) holds global(row, c8 ^ (row&7)); c8 = 16-byte column index (8 per row).
// Staging: lane i of instr j covers row j*8+(i>>3), chunk (i&7)^(i>>3) -> coalesced.
// Reads:   fragment chunk c8 of row r lives at c8 ^ (r&7) -> quarter-wave spans all
//          8 column groups, 2 lanes/bank (free) instead of 16-way same-group aliasing.
__global__ __launch_bounds__(256, 4) void phase1_kernel(
    const _Float16* __restrict__ qh, const _Float16* __restrict__ kh,
    const float* __restrict__ qtau,
    float* __restrict__ cand_s, int* __restrict__ cand_i, int* __restrict__ cnt) {
  __shared__ __align__(16) _Float16 As[QT * BK];     // 16 KB
  __shared__ __align__(16) _Float16 Bs[KTILE * BK];  // 16 KB (total 32 KB)

  const int tid = threadIdx.x;
  const int lane = tid & 63;
  const int wave = tid >> 6;
  const int qbase = blockIdx.x * QT;
  const int kbase = blockIdx.y * KTILE;

  // swizzled staging map (wave w covers rows [32w, 32w+32), instr j covers 8 rows)
  const int sr = lane >> 3;                       // row within 8-row instr group
  const int scol = (((lane & 7) ^ sr) << 3);      // XOR-swizzled 16B chunk
  const _Float16* gA = qh + (size_t)(qbase + wave * 32 + sr) * D_MODEL + scol;
  const _Float16* gB = kh + (size_t)(kbase + wave * 32 + sr) * D_MODEL + scol;
  _Float16* lA = As + (wave * 32) * BK;
  _Float16* lB = Bs + (wave * 32) * BK;

  const int wr = (wave >> 1) << 6;   // wave's query offset (0/64)
  const int wc = (wave & 1) << 6;    // wave's key offset   (0/64)
  const int lrow = lane & 15;
  const int lk8 = (lane >> 4) << 3;
  const int lxor = lrow & 7;         // read-side XOR (row&7 == lrow&7: wr,mi*16 are mult of 8)

  floatx4 acc[4][4] = {};

#pragma unroll
  for (int kt = 0; kt < D_MODEL / BK; ++kt) {
    const int k0 = kt * BK;
    __syncthreads();  // previous iteration's LDS readers done
#pragma unroll
    for (int j = 0; j < 4; ++j) {
      async_load16(gA + (size_t)(j * 8) * D_MODEL + k0, lA + (j * 8) * BK);
      async_load16(gB + (size_t)(j * 8) * D_MODEL + k0, lB + (j * 8) * BK);
    }
    __syncthreads();  // vmcnt(0) drain + barrier

#pragma unroll
    for (int kk = 0; kk < BK; kk += 32) {
      const int ca = ((((kk + lk8) >> 3) ^ lxor) << 3);  // swizzled byte-col (in f16 units)
      half8v a[4], b[4];
#pragma unroll
      for (int mi = 0; mi < 4; ++mi)
        a[mi] = *(const half8v*)(&As[(wr + mi * 16 + lrow) * BK + ca]);
#pragma unroll
      for (int ni = 0; ni < 4; ++ni)
        b[ni] = *(const half8v*)(&Bs[(wc + ni * 16 + lrow) * BK + ca]);
#pragma unroll
      for (int mi = 0; mi < 4; ++mi)
#pragma unroll
        for (int ni = 0; ni < 4; ++ni)
          acc[mi][ni] = __builtin_amdgcn_mfma_f32_16x16x32_f16(a[mi], b[ni], acc[mi][ni], 0, 0, 0);
    }
  }

  // epilogue: per-query threshold filter. C/D layout: col=lane&15, row=(lane>>4)*4+reg
  const int qrow0 = qbase + wr + ((lane >> 4) << 2);
#pragma unroll
  for (int mi = 0; mi < 4; ++mi) {
#pragma unroll
    for (int r = 0; r < 4; ++r) {
      const int q = qrow0 + mi * 16 + r;
      const float tau = qtau[q];
#pragma unroll
      for (int ni = 0; ni < 4; ++ni) {
        float dot = acc[mi][ni][r];
        if (dot > tau) {
          int kidx = kbase + wc + ni * 16 + lrow;
          int pos = atomicAdd(&cnt[q], 1);
          if (pos < CAP) {
            cand_s[(size_t)q * CAP + pos] = dot * 0.0625f;
            cand_i[(size_t)q * CAP + pos] = kidx;
          }
        }
      }
    }
  }
}

// ---------------- phase 2: per-query select/rescore/softmax/aggregate ----------------
__global__ __launch_bounds__(256) void phase2_kernel(
    const float* __restrict__ qf, const float* __restrict__ keys,
    const float* __restrict__ vals, const float* __restrict__ cand_s,
    const int* __restrict__ cand_i, const int* __restrict__ cnt,
    float* __restrict__ out) {
  __shared__ float sc[CAP];
  __shared__ int si[CAP];
  __shared__ float xs[RESCORE];
  __shared__ int xi[RESCORE];
  __shared__ float ew[TOPK];
  __shared__ float invsum;

  const int qid = blockIdx.x;
  const int tid = threadIdx.x;
  int c = cnt[qid];
  if (c > CAP) c = CAP;
  const int n = (c <= 256) ? 256 : CAP;  // block-uniform sort width

  for (int i = tid; i < n; i += 256) {
    bool valid = (i < c);
    sc[i] = valid ? cand_s[(size_t)qid * CAP + i] : -1e30f;
    si[i] = valid ? cand_i[(size_t)qid * CAP + i] : -1;
  }

  // bitonic sort descending by approx (f16-derived) score, width n
  for (int k = 2; k <= n; k <<= 1) {
    for (int j = k >> 1; j > 0; j >>= 1) {
      __syncthreads();
      for (int t = tid; t < n; t += 256) {
        int p = t ^ j;
        if (p > t) {
          float a = sc[t], b = sc[p];
          bool desc = ((t & k) == 0);
          if (desc ? (a < b) : (a > b)) {
            sc[t] = b; sc[p] = a;
            int tmp = si[t]; si[t] = si[p]; si[p] = tmp;
          }
        }
      }
    }
  }
  __syncthreads();

  // exact rescore (fp64 accumulate) of the top-64 candidates
  const int lane = tid & 63, wv = tid >> 6;
  const float4 qv = ((const float4*)(qf + (size_t)qid * D_MODEL))[lane];
  for (int cand = wv; cand < RESCORE; cand += 4) {
    int kidx = si[cand];  // wave-uniform
    float sres = -1e30f;
    if (kidx >= 0) {
      const float4 kv = ((const float4*)(keys + (size_t)kidx * D_MODEL))[lane];
      double p = (double)qv.x * kv.x + (double)qv.y * kv.y +
                 (double)qv.z * kv.z + (double)qv.w * kv.w;
#pragma unroll
      for (int off = 32; off > 0; off >>= 1) p += __shfl_down(p, off);
      sres = (float)(p * 0.0625);
    }
    if (lane == 0) { xs[cand] = sres; xi[cand] = kidx; }
  }
  __syncthreads();

  // bitonic sort descending by exact score, N = 64
  for (int k = 2; k <= RESCORE; k <<= 1) {
    for (int j = k >> 1; j > 0; j >>= 1) {
      __syncthreads();
      if (tid < RESCORE) {
        int t = tid, p = t ^ j;
        if (p > t) {
          float a = xs[t], b = xs[p];
          bool desc = ((t & k) == 0);
          if (desc ? (a < b) : (a > b)) {
            xs[t] = b; xs[p] = a;
            int tmp = xi[t]; xi[t] = xi[p]; xi[p] = tmp;
          }
        }
      }
    }
  }
  __syncthreads();

  // softmax over exact top-32 (xs[0] is the max — sorted)
  if (tid < TOPK) ew[tid] = expf(xs[tid] - xs[0]);
  __syncthreads();
  if (tid == 0) {
    float s = 0.f;
    for (int i = 0; i < TOPK; ++i) s += ew[i];
    invsum = 1.0f / s;
  }
  __syncthreads();

  // aggregate: thread d owns output dim d; coalesced value rows
  float acc = 0.f;
#pragma unroll 4
  for (int i = 0; i < TOPK; ++i)
    acc += (ew[i] * invsum) * vals[(size_t)xi[i] * D_MODEL + tid];
  out[(size_t)qid * D_MODEL + tid] = acc;
}

// ---------------- launcher ----------------
extern "C" void kernel_launch(void* const* d_in, const int* in_sizes, int n_in,
                              void* d_out, int out_size, void* d_ws, size_t ws_size,
                              hipStream_t stream) {
  const float* q = (const float*)d_in[0];   // [2048, 256]
  const float* k = (const float*)d_in[1];   // [65536, 256]
  const float* v = (const float*)d_in[2];   // [65536, 256]
  float* out = (float*)d_out;               // [2048, 256]

  char* ws = (char*)d_ws;
  _Float16* kh = (_Float16*)ws;                      // 33,554,432 B
  _Float16* qh = (_Float16*)(ws + 33554432);         //  1,048,576 B
  float* cand_s = (float*)(ws + 34603008);           //  4,194,304 B
  int* cand_i = (int*)(ws + 38797312);               //  4,194,304 B
  int* cnt = (int*)(ws + 42991616);                  //      8,192 B
  float* qtau = (float*)(ws + 42999808);             //      8,192 B

  hipMemsetAsync(cnt, 0, NQ * sizeof(int), stream);
  cvt_f32_f16<<<(M_KEYS * D_MODEL / 4 + 255) / 256, 256, 0, stream>>>(k, kh, M_KEYS * D_MODEL / 4);
  cvt_f32_f16<<<(NQ * D_MODEL / 4 + 255) / 256, 256, 0, stream>>>(q, qh, NQ * D_MODEL / 4);
  qtau_kernel<<<NQ / 4, 256, 0, stream>>>(q, qtau);

  dim3 g1(NQ / QT, M_KEYS / KTILE);
  phase1_kernel<<<g1, 256, 0, stream>>>(qh, kh, qtau, cand_s, cand_i, cnt);
  phase2_kernel<<<NQ, 256, 0, stream>>>(q, k, v, cand_s, cand_i, cnt, out);
}